// Round 13
// baseline (540.038 us; speedup 1.0000x reference)
//
#include <hip/hip_runtime.h>

#define T       256
#define BSHIFT  12
#define BSIZE   4096            // nodes per bucket
#define MAXNB   32              // max buckets (N<=131072)
#define M       32              // accumulate slices per bucket
#define EPB     4096            // edges per count/scatter block
#define EPT     (EPB / T)       // 16 edges per thread

// ---------- count: per-block bucket histogram -> plain-store matrix ----------
// cntT[b * ebp + g] = #edges of block g in bucket b   (transposed for scan)
// Block 0 also zeroes the 3 stage-completion counter arrays (96 ints).
__global__ void k_count(const int* __restrict__ col, int* __restrict__ cntT,
                        int* __restrict__ doneAll, int E, int nb, int ebp) {
    __shared__ int hist[MAXNB];
    int t = threadIdx.x, g = blockIdx.x;
    if (g == 0 && t < 3 * MAXNB) doneAll[t] = 0;
    if (t < MAXNB) hist[t] = 0;
    __syncthreads();
    int base = g * EPB;
    bool full = (base + EPB <= E);
    if (full) {
#pragma unroll
        for (int k = 0; k < EPT / 4; ++k) {
            int4 c = *(const int4*)(col + base + (t + k * T) * 4);
            atomicAdd(&hist[c.x >> BSHIFT], 1);
            atomicAdd(&hist[c.y >> BSHIFT], 1);
            atomicAdd(&hist[c.z >> BSHIFT], 1);
            atomicAdd(&hist[c.w >> BSHIFT], 1);
        }
    } else {
        for (int k = 0; k < EPT; ++k) {
            int e = base + t + k * T;
            if (e < E) atomicAdd(&hist[col[e] >> BSHIFT], 1);
        }
    }
    __syncthreads();
    if (t < nb) cntT[t * ebp + g] = hist[t];
}

// ---------- scan: one block per bucket, exclusive scan over eb blocks ----------
__global__ void k_scan(const int* __restrict__ cntT, int* __restrict__ ofsT,
                       int* __restrict__ tot, int eb, int ebp) {
    __shared__ int tsum[T];
    __shared__ int carry;
    int b = blockIdx.x, t = threadIdx.x;
    if (t == 0) carry = 0;
    __syncthreads();
    int rounds = (eb + T - 1) / T;
    for (int jr = 0; jr < rounds; ++jr) {
        int idx = jr * T + t;
        int v = (idx < eb) ? cntT[b * ebp + idx] : 0;
        tsum[t] = v;
        __syncthreads();
        for (int d = 1; d < T; d <<= 1) {
            int o = (t >= d) ? tsum[t - d] : 0;
            __syncthreads();
            tsum[t] += o;
            __syncthreads();
        }
        int excl = tsum[t] - v + carry;
        if (idx < eb) ofsT[b * ebp + idx] = excl;
        __syncthreads();
        if (t == 0) carry += tsum[T - 1];
        __syncthreads();
    }
    if (t == 0) tot[b] = carry;
}

// ---------- scatter: LDS bucket-sort one 4096-edge tile, coalesced copy-out ----------
// record.x = (col & 4095) << 17 | row  (row < 2^17), record.y = bits(w)
__global__ void k_scatter(const int* __restrict__ row, const int* __restrict__ col,
                          const float* __restrict__ w,
                          const int* __restrict__ cntT, const int* __restrict__ ofsT,
                          const int* __restrict__ tot,
                          int2* __restrict__ rec, int E, int nb, int ebp) {
    __shared__ int  lofs[MAXNB + 1];
    __shared__ int  rnk[MAXNB];
    __shared__ int  rbase[MAXNB];
    __shared__ int2 buf[EPB];          // 32 KB
    __shared__ unsigned char bkt[EPB]; // 4 KB
    int t = threadIdx.x, g = blockIdx.x;
    if (t < MAXNB) rnk[t] = 0;
    if (t < 64) {
        // scan padded tot (x4) -> bucket bases (exclusive), in-lane
        int tv = (t < nb) ? ((tot[t] + 3) & ~3) : 0;
        int incA = tv;
#pragma unroll
        for (int d = 1; d < 32; d <<= 1) {
            int o = __shfl_up(incA, d, 64);
            if (t >= d) incA += o;
        }
        // scan this block's count row -> tile-local offsets
        int h = (t < nb) ? cntT[t * ebp + g] : 0;
        int incB = h;
#pragma unroll
        for (int d = 1; d < 32; d <<= 1) {
            int o = __shfl_up(incB, d, 64);
            if (t >= d) incB += o;
        }
        if (t == 0) lofs[0] = 0;
        if (t < nb) {
            lofs[t + 1] = incB;
            rbase[t] = (incA - tv) + ofsT[t * ebp + g];   // bucket base + my offset
        }
    }
    __syncthreads();

    int base = g * EPB;
    bool full = (base + EPB <= E);
    if (full) {
#pragma unroll
        for (int k = 0; k < EPT / 4; ++k) {
            int idx = base + (t + k * T) * 4;
            int4   c  = *(const int4*)(col + idx);
            int4   r  = *(const int4*)(row + idx);
            float4 wv = *(const float4*)(w + idx);
            int b, rk, pos;
            b = c.x >> BSHIFT; rk = atomicAdd(&rnk[b], 1); pos = lofs[b] + rk;
            buf[pos] = make_int2(((c.x & (BSIZE-1)) << 17) | r.x, __float_as_int(wv.x));
            bkt[pos] = (unsigned char)b;
            b = c.y >> BSHIFT; rk = atomicAdd(&rnk[b], 1); pos = lofs[b] + rk;
            buf[pos] = make_int2(((c.y & (BSIZE-1)) << 17) | r.y, __float_as_int(wv.y));
            bkt[pos] = (unsigned char)b;
            b = c.z >> BSHIFT; rk = atomicAdd(&rnk[b], 1); pos = lofs[b] + rk;
            buf[pos] = make_int2(((c.z & (BSIZE-1)) << 17) | r.z, __float_as_int(wv.z));
            bkt[pos] = (unsigned char)b;
            b = c.w >> BSHIFT; rk = atomicAdd(&rnk[b], 1); pos = lofs[b] + rk;
            buf[pos] = make_int2(((c.w & (BSIZE-1)) << 17) | r.w, __float_as_int(wv.w));
            bkt[pos] = (unsigned char)b;
        }
    } else {
        for (int k = 0; k < EPT; ++k) {
            int e = base + t + k * T;
            if (e < E) {
                int c = col[e];
                int b = c >> BSHIFT;
                int rk = atomicAdd(&rnk[b], 1);
                int pos = lofs[b] + rk;
                buf[pos] = make_int2(((c & (BSIZE-1)) << 17) | row[e], __float_as_int(w[e]));
                bkt[pos] = (unsigned char)b;
            }
        }
    }
    __syncthreads();
    int total = lofs[nb];
    for (int j = t; j < total; j += T) {       // coalesced copy-out
        int b = bkt[j];
        rec[rbase[b] + (j - lofs[b])] = buf[j];
    }
}

// ---------- accumulate + fused epilogue (last-block-per-bucket reduce) ----------
// STAGE 0: degree -> dinv, p    STAGE 1: layer1 + MLP -> q    STAGE 2: layer2 -> out
template <int STAGE>
__global__ void k_acc(const int2* __restrict__ rec, const int* __restrict__ tot,
                      float* __restrict__ part, int* __restrict__ done,
                      const float* __restrict__ x,
                      float* __restrict__ dinv, float* __restrict__ p,
                      float* __restrict__ q,
                      const float* __restrict__ W1, const float* __restrict__ b1,
                      const float* __restrict__ W2, const float* __restrict__ b2,
                      float* __restrict__ out, int N, int nb) {
    __shared__ float acc[BSIZE];
    __shared__ int   bst[MAXNB];
    __shared__ int   tick;
    const float* src = (STAGE == 1) ? p : ((STAGE == 2) ? q : nullptr);
    int t = threadIdx.x, g = blockIdx.x;
    int b = g / M, m = g % M;
    if (t < 64) {                               // bucket bases from padded tot
        int tv = (t < nb) ? ((tot[t] + 3) & ~3) : 0;
        int inc = tv;
#pragma unroll
        for (int d = 1; d < 32; d <<= 1) {
            int o = __shfl_up(inc, d, 64);
            if (t >= d) inc += o;
        }
        if (t < nb) bst[t] = inc - tv;
    }
    for (int j = t; j < BSIZE; j += T) acc[j] = 0.0f;
    __syncthreads();
    int s  = bst[b];
    int tb = tot[b];
    int chunk = ((tb + M - 1) / M + 7) & ~7;    // x8 records per slice
    int lo = s + m * chunk;
    int hi = min(s + tb, lo + chunk);
    const int4* rec4 = (const int4*)rec;
    int i = lo + t * 8;
    for (; i + 7 < hi; i += T * 8) {
        int4 q0 = rec4[(i >> 1) + 0];
        int4 q1 = rec4[(i >> 1) + 1];
        int4 q2 = rec4[(i >> 1) + 2];
        int4 q3 = rec4[(i >> 1) + 3];
        float v0 = __int_as_float(q0.y), v1 = __int_as_float(q0.w);
        float v2 = __int_as_float(q1.y), v3 = __int_as_float(q1.w);
        float v4 = __int_as_float(q2.y), v5 = __int_as_float(q2.w);
        float v6 = __int_as_float(q3.y), v7 = __int_as_float(q3.w);
        if (STAGE != 0) {
            v0 *= src[q0.x & 0x1FFFF]; v1 *= src[q0.z & 0x1FFFF];
            v2 *= src[q1.x & 0x1FFFF]; v3 *= src[q1.z & 0x1FFFF];
            v4 *= src[q2.x & 0x1FFFF]; v5 *= src[q2.z & 0x1FFFF];
            v6 *= src[q3.x & 0x1FFFF]; v7 *= src[q3.z & 0x1FFFF];
        }
        atomicAdd(&acc[((unsigned)q0.x) >> 17], v0);
        atomicAdd(&acc[((unsigned)q0.z) >> 17], v1);
        atomicAdd(&acc[((unsigned)q1.x) >> 17], v2);
        atomicAdd(&acc[((unsigned)q1.z) >> 17], v3);
        atomicAdd(&acc[((unsigned)q2.x) >> 17], v4);
        atomicAdd(&acc[((unsigned)q2.z) >> 17], v5);
        atomicAdd(&acc[((unsigned)q3.x) >> 17], v6);
        atomicAdd(&acc[((unsigned)q3.z) >> 17], v7);
    }
    for (; i < hi; ++i) {                       // tail owned by exactly one thread
        int2 r = rec[i];
        float v = __int_as_float(r.y);
        if (STAGE != 0) v *= src[r.x & 0x1FFFF];
        atomicAdd(&acc[((unsigned)r.x) >> 17], v);
    }
    __syncthreads();
    float* dst = part + (size_t)g * BSIZE;
    for (int j = t; j < BSIZE; j += T) dst[j] = acc[j];

    // ---- publish partial, take ticket; last block reduces + epilogue ----
    __threadfence();                            // release: flush part stores
    if (t == 0) tick = atomicAdd(&done[b], 1);  // device-scope
    __syncthreads();
    if (tick != M - 1) return;
    __threadfence();                            // acquire: invalidate stale lines
    int nodebase = b << BSHIFT;
    for (int j = t; j < BSIZE; j += T) {
        int n = nodebase + j;
        if (n >= N) break;
        const float* pp = part + (size_t)b * M * BSIZE + j;
        float ssum = 0.0f;
#pragma unroll
        for (int mm = 0; mm < M; ++mm) ssum += pp[(size_t)mm * BSIZE];
        if (STAGE == 0) {
            float d  = ssum + 1.0f;             // +1 = self-loop
            float di = rsqrtf(d);
            dinv[n] = di;
            p[n] = di * x[n];
        } else if (STAGE == 1) {
            float di = dinv[n];
            float sv = di * ssum + di * p[n];
            float a = 0.0f;
#pragma unroll
            for (int k = 0; k < 16; ++k) {
                float h = fmaxf(sv * W1[k] + b1[k], 0.0f);
                a += h * W2[k];
            }
            q[n] = di * a;
        } else {
            float di = dinv[n];
            out[n] = di * ssum + di * q[n] + b2[0];
        }
    }
}

extern "C" void kernel_launch(void* const* d_in, const int* in_sizes, int n_in,
                              void* d_out, int out_size, void* d_ws, size_t ws_size,
                              hipStream_t stream) {
    const float* x  = (const float*)d_in[0];
    const int*   ei = (const int*)  d_in[1];
    const float* ew = (const float*)d_in[2];
    const float* W1 = (const float*)d_in[3];
    const float* b1 = (const float*)d_in[4];
    const float* W2 = (const float*)d_in[5];
    const float* b2 = (const float*)d_in[6];

    const int N = in_sizes[0];       // x is [N,1]
    const int E = in_sizes[2];       // edge_attr is [E]
    const int* row = ei;             // edge_index[0] = source
    const int* col = ei + E;         // edge_index[1] = target
    const int nb  = (N + BSIZE - 1) >> BSHIFT;   // 25
    const int eb  = (E + EPB - 1) / EPB;         // 1221
    const int ebp = (eb + 63) & ~63;             // padded row length

    // workspace layout (~54.8 MB), 256 B aligned
    char* wsp = (char*)d_ws;
    auto take = [&](size_t bytes) {
        char* r = wsp; wsp += (bytes + 255) & ~(size_t)255; return (void*)r;
    };
    int2*  rec  = (int2*) take((size_t)(E + 4 * MAXNB) * 8);   // 40.07 MB
    float* part = (float*)take((size_t)nb * M * BSIZE * 4);    // 13.11 MB
    float* dinv = (float*)take((size_t)N * 4);
    float* p    = (float*)take((size_t)N * 4);
    float* q    = (float*)take((size_t)N * 4);
    int*   cntT = (int*)  take((size_t)MAXNB * ebp * 4);       // 0.16 MB
    int*   ofsT = (int*)  take((size_t)MAXNB * ebp * 4);       // 0.16 MB
    int*   tot  = (int*)  take(MAXNB * 4);
    int*   done = (int*)  take(3 * MAXNB * 4);                 // stage tickets

    float* out = (float*)d_out;
    const int ab = nb * M;                       // 800

    k_count  <<<eb, T, 0, stream>>>(col, cntT, done, E, nb, ebp);
    k_scan   <<<nb, T, 0, stream>>>(cntT, ofsT, tot, eb, ebp);
    k_scatter<<<eb, T, 0, stream>>>(row, col, ew, cntT, ofsT, tot, rec, E, nb, ebp);

    k_acc<0><<<ab, T, 0, stream>>>(rec, tot, part, done + 0 * MAXNB,
                                   x, dinv, p, q, W1, b1, W2, b2, out, N, nb);
    k_acc<1><<<ab, T, 0, stream>>>(rec, tot, part, done + 1 * MAXNB,
                                   x, dinv, p, q, W1, b1, W2, b2, out, N, nb);
    k_acc<2><<<ab, T, 0, stream>>>(rec, tot, part, done + 2 * MAXNB,
                                   x, dinv, p, q, W1, b1, W2, b2, out, N, nb);
}